// Round 4
// baseline (733.872 us; speedup 1.0000x reference)
//
#include <hip/hip_runtime.h>

typedef __bf16 bf16x8 __attribute__((ext_vector_type(8)));
typedef float f32x4 __attribute__((ext_vector_type(4)));

constexpr int NN = 50000;   // nodes
constexpr int NE = 800000;  // edges
constexpr int DIN = 256, DHID = 256, DOUT = 128;
constexpr int NCH = (NN + 255) / 256;  // 196 chunks of 256
constexpr int NGRP = (NN + 63) / 64;   // 782 groups of 64 nodes

__device__ __forceinline__ unsigned short f2bf(float f) {
  unsigned u = __float_as_uint(f);
  u += 0x7fffu + ((u >> 16) & 1u);  // RNE
  return (unsigned short)(u >> 16);
}
__device__ __forceinline__ float bf2f(unsigned short h) {
  return __uint_as_float(((unsigned)h) << 16);
}

// accumulate 4 bf16 (packed in uint2) into a[4]
__device__ __forceinline__ void acc4(float a[4], uint2 v) {
  a[0] += __uint_as_float(v.x << 16);
  a[1] += __uint_as_float(v.x & 0xffff0000u);
  a[2] += __uint_as_float(v.y << 16);
  a[3] += __uint_as_float(v.y & 0xffff0000u);
}
__device__ __forceinline__ void acc4m(float a[4], uint2 v, float m) {
  a[0] = fmaf(m, __uint_as_float(v.x << 16), a[0]);
  a[1] = fmaf(m, __uint_as_float(v.x & 0xffff0000u), a[1]);
  a[2] = fmaf(m, __uint_as_float(v.y << 16), a[2]);
  a[3] = fmaf(m, __uint_as_float(v.y & 0xffff0000u), a[3]);
}

// ---------------- CSR build ----------------

__global__ void hist_kernel(const int* __restrict__ e0, const int* __restrict__ e1,
                            int* __restrict__ counts) {
  int g = blockIdx.y;
  const int* dst = (g ? e1 : e0) + NE;  // edge_index row 1
  int* c = counts + g * NN;
  int i = blockIdx.x * blockDim.x + threadIdx.x;
  if (i < NE) atomicAdd(&c[dst[i]], 1);
}

__global__ __launch_bounds__(256) void scanA_kernel(const int* __restrict__ counts,
                                                    int* __restrict__ bsum) {
  int g = blockIdx.y, chunk = blockIdx.x, t = threadIdx.x;
  int i = chunk * 256 + t;
  int v = (i < NN) ? counts[g * NN + i] : 0;
  __shared__ int sh[256];
  sh[t] = v;
  __syncthreads();
  for (int off = 128; off > 0; off >>= 1) {
    if (t < off) sh[t] += sh[t + off];
    __syncthreads();
  }
  if (t == 0) bsum[g * NCH + chunk] = sh[0];
}

__global__ __launch_bounds__(256) void scanB_kernel(int* __restrict__ bsum,
                                                    int* __restrict__ rowptr) {
  int g = blockIdx.x, t = threadIdx.x;
  int v = (t < NCH) ? bsum[g * NCH + t] : 0;
  __shared__ int sh[256];
  sh[t] = v;
  __syncthreads();
  for (int off = 1; off < 256; off <<= 1) {
    int x = (t >= off) ? sh[t - off] : 0;
    __syncthreads();
    if (t >= off) sh[t] += x;
    __syncthreads();
  }
  if (t < NCH) bsum[g * NCH + t] = sh[t] - v;  // exclusive base
  if (t == 255) rowptr[g * (NN + 1) + NN] = sh[255];
}

__global__ __launch_bounds__(256) void scanC_kernel(const int* __restrict__ counts,
                                                    const int* __restrict__ bsum,
                                                    int* __restrict__ rowptr,
                                                    int* __restrict__ cursor,
                                                    float* __restrict__ dinv) {
  int g = blockIdx.y, chunk = blockIdx.x, t = threadIdx.x;
  int i = chunk * 256 + t;
  int v = (i < NN) ? counts[g * NN + i] : 0;
  __shared__ int sh[256];
  sh[t] = v;
  __syncthreads();
  for (int off = 1; off < 256; off <<= 1) {
    int x = (t >= off) ? sh[t - off] : 0;
    __syncthreads();
    if (t >= off) sh[t] += x;
    __syncthreads();
  }
  if (i < NN) {
    int run = bsum[g * NCH + chunk] + sh[t] - v;
    rowptr[g * (NN + 1) + i] = run;
    cursor[g * NN + i] = run;
    dinv[g * NN + i] = rsqrtf((float)(v + 1));  // +1 self-loop
  }
}

__global__ void scatter_kernel(const int* __restrict__ e0, const int* __restrict__ e1,
                               int* __restrict__ cursor, unsigned short* __restrict__ col) {
  int g = blockIdx.y;
  const int* e = g ? e1 : e0;
  int* cur = cursor + g * NN;
  unsigned short* cl = col + g * NE;
  int i = blockIdx.x * blockDim.x + threadIdx.x;
  if (i < NE) {
    int s = e[i], d = e[NE + i];
    int slot = atomicAdd(&cur[d], 1);
    cl[slot] = (unsigned short)s;
  }
}

// ---------------- Pack W into B-fragment order ----------------
// Wpack flat index: ((kb*NT + nt)*64 + lane)*8 + j  holds W[kb*32 + (lane>>4)*8 + j][nt*16 + (lane&15)]

__global__ void pack_kernel(const float* __restrict__ W1, const float* __restrict__ W2,
                            unsigned short* __restrict__ P1, unsigned short* __restrict__ P2) {
  int i = blockIdx.x * blockDim.x + threadIdx.x;
  constexpr int N1 = 8 * 16 * 64 * 8;  // 65536 (K=256, N=256)
  constexpr int N2 = 8 * 8 * 64 * 8;   // 32768 (K=256, N=128)
  if (i < N1) {
    int j = i & 7, lane = (i >> 3) & 63, grp = i >> 9;
    int nt = grp & 15, kb = grp >> 4;
    int k = kb * 32 + (lane >> 4) * 8 + j;
    int n = nt * 16 + (lane & 15);
    P1[i] = f2bf(W1[k * DHID + n]);
  } else if (i < N1 + N2) {
    int ii = i - N1;
    int j = ii & 7, lane = (ii >> 3) & 63, grp = ii >> 9;
    int nt = grp & 7, kb = grp >> 3;
    int k = kb * 32 + (lane >> 4) * 8 + j;
    int n = nt * 16 + (lane & 15);
    P2[ii] = f2bf(W2[k * DOUT + n]);
  }
}

// ---------------- mm1: m1c = (x @ W1) * dinv[row], CHUNK-MAJOR bf16 ----------------
// m1c layout: [g][chunk 0..7][node][32 cols]; chunk = col>>5.

__global__ __launch_bounds__(256) void mm1_kernel(
    const float* __restrict__ A0, const float* __restrict__ A1,
    const unsigned short* __restrict__ Wp, unsigned short* __restrict__ m1c,
    const float* __restrict__ dinv) {
  constexpr int N = DHID, NT = N / 16, K = 256;
  int g = blockIdx.y;
  const float* A = g ? A1 : A0;
  unsigned short* C = m1c + (size_t)g * 8 * NN * 32;
  const float* dv = dinv + g * NN;
  int wave = threadIdx.x >> 6, lane = threadIdx.x & 63;
  int q = lane >> 4, lm = lane & 15;
  int m0 = blockIdx.x * 64 + wave * 16;
  int rowc = min(m0 + lm, NN - 1);
  f32x4 acc[NT];
#pragma unroll
  for (int nt = 0; nt < NT; nt++) acc[nt] = (f32x4){0.f, 0.f, 0.f, 0.f};
#pragma unroll
  for (int kb = 0; kb < K / 32; kb++) {
    int kc = kb * 32 + q * 8;
    const float* Af = A + (size_t)rowc * K + kc;
    const float4 v0 = *(const float4*)Af;
    const float4 v1 = *(const float4*)(Af + 4);
    bf16x8 a;
    a[0] = (__bf16)v0.x; a[1] = (__bf16)v0.y; a[2] = (__bf16)v0.z; a[3] = (__bf16)v0.w;
    a[4] = (__bf16)v1.x; a[5] = (__bf16)v1.y; a[6] = (__bf16)v1.z; a[7] = (__bf16)v1.w;
#pragma unroll
    for (int nt = 0; nt < NT; nt++) {
      bf16x8 b = *(const bf16x8*)(Wp + (((size_t)kb * NT + nt) * 64 + lane) * 8);
      acc[nt] = __builtin_amdgcn_mfma_f32_16x16x32_bf16(a, b, acc[nt], 0, 0, 0);
    }
  }
  float dvr[4];
#pragma unroll
  for (int r = 0; r < 4; r++) dvr[r] = dv[min(m0 + q * 4 + r, NN - 1)];
#pragma unroll
  for (int nt = 0; nt < NT; nt++) {
#pragma unroll
    for (int r = 0; r < 4; r++) {
      int grow = m0 + q * 4 + r;
      if (grow < NN)
        C[((size_t)(nt >> 1) * NN + grow) * 32 + (nt & 1) * 16 + lm] =
            f2bf(acc[nt][r] * dvr[r]);
    }
  }
}

// ---------------- agg1c: XCD-sharded gather-aggregate of one 32-col chunk ----------
// blockIdx.x & 7 = chunk -> lands on a fixed XCD (round-robin dispatch); the
// chunk's slice of m1c is 3.2 MB -> L2-resident. blockIdx.y = graph (slow).
// Wave: slot=lane>>3 covers edge j+slot; sub=lane&7 covers cols sub*4..+3 (8 B).
// Indices preloaded once into a register (cl[jb+lane], clamped) and fetched per
// round via shuffle -> no dependent index-load in the chain. 3-level shfl_xor
// tree reduces the 8 slots; self row + dinv + bias + relu; a1c chunk-major.

__global__ __launch_bounds__(256) void agg1c_kernel(
    const unsigned short* __restrict__ m1c, unsigned short* __restrict__ a1c,
    const int* __restrict__ rowptr, const unsigned short* __restrict__ col,
    const float* __restrict__ dinv, const float* __restrict__ b1) {
  int chunk = blockIdx.x & 7, ngrp = blockIdx.x >> 3, g = blockIdx.y;
  const unsigned short* Hc = m1c + ((size_t)g * 8 + chunk) * ((size_t)NN * 32);
  unsigned short* Ac = a1c + ((size_t)g * 8 + chunk) * ((size_t)NN * 32);
  const int* rp = rowptr + g * (NN + 1);
  const unsigned short* cl = col + (size_t)g * NE;
  const float* dv = dinv + g * NN;
  int wave = threadIdx.x >> 6, lane = threadIdx.x & 63;
  int slot = lane >> 3, sub = lane & 7;
  float4 bb = *(const float4*)(b1 + chunk * 32 + sub * 4);
  int nbase = ngrp * 64 + wave * 16;
  for (int n = 0; n < 16; n++) {
    int node = nbase + n;
    if (node >= NN) break;
    int jb = rp[node], je = rp[node + 1];
    int last = max(je - 1, 0);
    int sid = cl[min(jb + lane, last)];  // clamped index preload (covers deg<=64)
    float a[4] = {0.f, 0.f, 0.f, 0.f};
    int j = jb, rr = 0;
    for (; j + 8 <= je && rr < 8; j += 8, rr++) {
      int s = __shfl(sid, rr * 8 + slot, 64);
      uint2 v = *(const uint2*)(Hc + (size_t)s * 32 + sub * 4);
      acc4(a, v);
    }
    for (; j + 8 <= je; j += 8) {  // deg > 64 (cold path)
      int s = cl[j + slot];
      uint2 v = *(const uint2*)(Hc + (size_t)s * 32 + sub * 4);
      acc4(a, v);
    }
    if (j < je) {  // masked tail round
      int idx = j + slot;
      int s = (rr < 8) ? __shfl(sid, rr * 8 + slot, 64) : cl[min(idx, je - 1)];
      uint2 v = *(const uint2*)(Hc + (size_t)s * 32 + sub * 4);
      acc4m(a, v, (idx < je) ? 1.f : 0.f);
    }
    // reduce 8 slots (lane bits 3,4,5)
#pragma unroll
    for (int i = 0; i < 4; i++) {
      a[i] += __shfl_xor(a[i], 8, 64);
      a[i] += __shfl_xor(a[i], 16, 64);
      a[i] += __shfl_xor(a[i], 32, 64);
    }
    // self row (all slot-groups load identical 8 B -> consistent)
    uint2 sv = *(const uint2*)(Hc + (size_t)node * 32 + sub * 4);
    acc4(a, sv);
    float di = dv[node];
    ushort4 o;
    o.x = f2bf(fmaxf(fmaf(a[0], di, bb.x), 0.f));
    o.y = f2bf(fmaxf(fmaf(a[1], di, bb.y), 0.f));
    o.z = f2bf(fmaxf(fmaf(a[2], di, bb.z), 0.f));
    o.w = f2bf(fmaxf(fmaf(a[3], di, bb.w), 0.f));
    if (lane < 8) *(ushort4*)(Ac + (size_t)node * 32 + sub * 4) = o;
  }
}

// ---------------- mm2: m2c = (a1 @ W2) * dinv, dense GEMM ----------------
// a1c chunk-major IS the A-frag layout (k-chunk kb == col-chunk kb).
// m2c written chunk-major for agg2c: [g][chunk 0..3][node][32].

__global__ __launch_bounds__(256) void mm2_kernel(
    const unsigned short* __restrict__ a1c, const unsigned short* __restrict__ P2,
    unsigned short* __restrict__ m2c, const float* __restrict__ dinv) {
  constexpr int NT2 = DOUT / 16;  // 8
  int g = blockIdx.y;
  const unsigned short* A = a1c + (size_t)g * 8 * NN * 32;
  unsigned short* C = m2c + (size_t)g * 4 * NN * 32;
  const float* dv = dinv + g * NN;
  int wave = threadIdx.x >> 6, lane = threadIdx.x & 63;
  int q = lane >> 4, lm = lane & 15;
  int m0 = blockIdx.x * 64 + wave * 16;
  int rowc = min(m0 + lm, NN - 1);
  f32x4 acc[NT2];
#pragma unroll
  for (int nt = 0; nt < NT2; nt++) acc[nt] = (f32x4){0.f, 0.f, 0.f, 0.f};
#pragma unroll
  for (int kb = 0; kb < 8; kb++) {
    bf16x8 a = *(const bf16x8*)(A + ((size_t)kb * NN + rowc) * 32 + q * 8);
#pragma unroll
    for (int nt = 0; nt < NT2; nt++) {
      bf16x8 b = *(const bf16x8*)(P2 + (((size_t)kb * NT2 + nt) * 64 + lane) * 8);
      acc[nt] = __builtin_amdgcn_mfma_f32_16x16x32_bf16(a, b, acc[nt], 0, 0, 0);
    }
  }
  float dvr[4];
#pragma unroll
  for (int r = 0; r < 4; r++) dvr[r] = dv[min(m0 + q * 4 + r, NN - 1)];
#pragma unroll
  for (int nt = 0; nt < NT2; nt++) {
#pragma unroll
    for (int r = 0; r < 4; r++) {
      int grow = m0 + q * 4 + r;
      if (grow < NN)
        C[((size_t)(nt >> 1) * NN + grow) * 32 + (nt & 1) * 16 + lm] =
            f2bf(acc[nt][r] * dvr[r]);
    }
  }
}

// ---------------- agg2c: XCD-sharded final aggregate -> out (f32) ----------------
// 4 chunks x 2 graphs = 8 shards <-> 8 XCDs; each shard slice = 3.2 MB L2-fit.

__global__ __launch_bounds__(256) void agg2c_kernel(
    const unsigned short* __restrict__ m2c, float* __restrict__ out,
    const int* __restrict__ rowptr, const unsigned short* __restrict__ col,
    const float* __restrict__ dinv, const float* __restrict__ b2) {
  int shard = blockIdx.x & 7, ngrp = blockIdx.x >> 3;
  int chunk = shard >> 1, g = shard & 1;
  const unsigned short* Hc = m2c + ((size_t)g * 4 + chunk) * ((size_t)NN * 32);
  float* O = out + (size_t)g * NN * DOUT;
  const int* rp = rowptr + g * (NN + 1);
  const unsigned short* cl = col + (size_t)g * NE;
  const float* dv = dinv + g * NN;
  int wave = threadIdx.x >> 6, lane = threadIdx.x & 63;
  int slot = lane >> 3, sub = lane & 7;
  float4 bb = *(const float4*)(b2 + chunk * 32 + sub * 4);
  int nbase = ngrp * 64 + wave * 16;
  for (int n = 0; n < 16; n++) {
    int node = nbase + n;
    if (node >= NN) break;
    int jb = rp[node], je = rp[node + 1];
    int last = max(je - 1, 0);
    int sid = cl[min(jb + lane, last)];
    float a[4] = {0.f, 0.f, 0.f, 0.f};
    int j = jb, rr = 0;
    for (; j + 8 <= je && rr < 8; j += 8, rr++) {
      int s = __shfl(sid, rr * 8 + slot, 64);
      uint2 v = *(const uint2*)(Hc + (size_t)s * 32 + sub * 4);
      acc4(a, v);
    }
    for (; j + 8 <= je; j += 8) {
      int s = cl[j + slot];
      uint2 v = *(const uint2*)(Hc + (size_t)s * 32 + sub * 4);
      acc4(a, v);
    }
    if (j < je) {
      int idx = j + slot;
      int s = (rr < 8) ? __shfl(sid, rr * 8 + slot, 64) : cl[min(idx, je - 1)];
      uint2 v = *(const uint2*)(Hc + (size_t)s * 32 + sub * 4);
      acc4m(a, v, (idx < je) ? 1.f : 0.f);
    }
#pragma unroll
    for (int i = 0; i < 4; i++) {
      a[i] += __shfl_xor(a[i], 8, 64);
      a[i] += __shfl_xor(a[i], 16, 64);
      a[i] += __shfl_xor(a[i], 32, 64);
    }
    uint2 sv = *(const uint2*)(Hc + (size_t)node * 32 + sub * 4);
    acc4(a, sv);
    float di = dv[node];
    float4 o;
    o.x = fmaf(a[0], di, bb.x);
    o.y = fmaf(a[1], di, bb.y);
    o.z = fmaf(a[2], di, bb.z);
    o.w = fmaf(a[3], di, bb.w);
    if (lane < 8) *(float4*)(O + (size_t)node * DOUT + chunk * 32 + sub * 4) = o;
  }
}

// ---------------- launch ----------------

extern "C" void kernel_launch(void* const* d_in, const int* in_sizes, int n_in,
                              void* d_out, int out_size, void* d_ws, size_t ws_size,
                              hipStream_t stream) {
  const float* x1 = (const float*)d_in[0];
  const int* e1 = (const int*)d_in[1];
  const float* x2 = (const float*)d_in[2];
  const int* e2 = (const int*)d_in[3];
  const float* W1 = (const float*)d_in[4];
  const float* b1 = (const float*)d_in[5];
  const float* W2 = (const float*)d_in[6];
  const float* b2 = (const float*)d_in[7];
  float* out = (float*)d_out;

  char* base = (char*)d_ws;
  size_t off = 0;
  auto alloc = [&](size_t bytes) -> void* {
    void* p = base + off;
    off = (off + bytes + 511) & ~(size_t)511;
    return p;
  };
  int* counts = (int*)alloc((size_t)2 * NN * 4);
  int* rowptr = (int*)alloc((size_t)2 * (NN + 1) * 4);
  int* cursor = (int*)alloc((size_t)2 * NN * 4);
  float* dinv = (float*)alloc((size_t)2 * NN * 4);
  int* bsum = (int*)alloc((size_t)2 * NCH * 4);
  unsigned short* col = (unsigned short*)alloc((size_t)2 * NE * 2);
  unsigned short* m1c = (unsigned short*)alloc((size_t)2 * 8 * NN * 32 * 2);  // 51.2 MB
  unsigned short* a1c = (unsigned short*)alloc((size_t)2 * 8 * NN * 32 * 2);  // 51.2 MB
  unsigned short* m2c = m1c;  // reuse: m1c dead after agg1c
  unsigned short* P1 = (unsigned short*)alloc((size_t)8 * 16 * 64 * 8 * 2);
  unsigned short* P2 = (unsigned short*)alloc((size_t)8 * 8 * 64 * 8 * 2);

  hipMemsetAsync(counts, 0, (size_t)2 * NN * 4, stream);
  hist_kernel<<<dim3((NE + 255) / 256, 2), 256, 0, stream>>>(e1, e2, counts);
  scanA_kernel<<<dim3(NCH, 2), 256, 0, stream>>>(counts, bsum);
  scanB_kernel<<<2, 256, 0, stream>>>(bsum, rowptr);
  scanC_kernel<<<dim3(NCH, 2), 256, 0, stream>>>(counts, bsum, rowptr, cursor, dinv);
  scatter_kernel<<<dim3((NE + 255) / 256, 2), 256, 0, stream>>>(e1, e2, cursor, col);
  pack_kernel<<<(98304 + 255) / 256, 256, 0, stream>>>(W1, W2, P1, P2);
  // layer 1 mm: m1c = (x @ W1) * dinv (bf16, chunk-major)
  mm1_kernel<<<dim3(NGRP, 2), 256, 0, stream>>>(x1, x2, P1, m1c, dinv);
  // sharded agg1: a1c = relu(agg(m1c)*dinv + b1) per 32-col chunk (XCD-local)
  agg1c_kernel<<<dim3(8 * NGRP, 2), 256, 0, stream>>>(m1c, a1c, rowptr, col, dinv, b1);
  // layer 2 mm: m2c = (a1 @ W2) * dinv (bf16, chunk-major)
  mm2_kernel<<<dim3(NGRP, 2), 256, 0, stream>>>(a1c, P2, m2c, dinv);
  // sharded agg2: out = agg(m2c)*dinv + b2 (f32)
  agg2c_kernel<<<dim3(8 * NGRP, 1), 256, 0, stream>>>(m2c, out, rowptr, col, dinv, b2);
}

// Round 5
// 533.779 us; speedup vs baseline: 1.3749x; 1.3749x over previous
//
#include <hip/hip_runtime.h>

typedef __bf16 bf16x8 __attribute__((ext_vector_type(8)));
typedef float f32x4 __attribute__((ext_vector_type(4)));
typedef unsigned short us8 __attribute__((ext_vector_type(8)));

constexpr int NN = 50000;   // nodes
constexpr int NE = 800000;  // edges
constexpr int NNP = NN + 8;           // slice row stride (row NN = zero row)
constexpr int NEP = NE + 8 * NN;      // padded CSR capacity (1.2M slots)
constexpr int DIN = 256, DHID = 256, DOUT = 128;
constexpr int NCH = (NN + 255) / 256;  // 196 chunks of 256
constexpr int NGRP = (NN + 63) / 64;   // 782 groups of 64 nodes

__device__ __forceinline__ unsigned short f2bf(float f) {
  unsigned u = __float_as_uint(f);
  u += 0x7fffu + ((u >> 16) & 1u);  // RNE
  return (unsigned short)(u >> 16);
}

// accumulate 8 bf16 (packed in uint4) into a[8]
__device__ __forceinline__ void acc8(float a[8], uint4 v) {
  a[0] += __uint_as_float(v.x << 16);
  a[1] += __uint_as_float(v.x & 0xffff0000u);
  a[2] += __uint_as_float(v.y << 16);
  a[3] += __uint_as_float(v.y & 0xffff0000u);
  a[4] += __uint_as_float(v.z << 16);
  a[5] += __uint_as_float(v.z & 0xffff0000u);
  a[6] += __uint_as_float(v.w << 16);
  a[7] += __uint_as_float(v.w & 0xffff0000u);
}

// ---------------- pad helpers ----------------

__global__ void fillcol_kernel(unsigned short* __restrict__ col) {
  constexpr int TOT = 2 * NEP / 8;  // uint4 count
  int i = blockIdx.x * blockDim.x + threadIdx.x;
  unsigned v = (unsigned)NN | ((unsigned)NN << 16);
  if (i < TOT) ((uint4*)col)[i] = (uint4){v, v, v, v};
}

// zero row NN of each of the 16 chunk slices (serves m1c and m2c phases)
__global__ void zrow_kernel(unsigned short* __restrict__ m1c) {
  int t = threadIdx.x;  // 512 threads = 16 slices x 32 cols
  int s = t >> 5, c = t & 31;
  m1c[(size_t)s * NNP * 32 + (size_t)NN * 32 + c] = 0;
}

// ---------------- CSR build (8-aligned padded segments) ----------------

__global__ void hist_kernel(const int* __restrict__ e0, const int* __restrict__ e1,
                            int* __restrict__ counts) {
  int g = blockIdx.y;
  const int* dst = (g ? e1 : e0) + NE;  // edge_index row 1
  int* c = counts + g * NN;
  int i = blockIdx.x * blockDim.x + threadIdx.x;
  if (i < NE) atomicAdd(&c[dst[i]], 1);
}

__global__ __launch_bounds__(256) void scanA_kernel(const int* __restrict__ counts,
                                                    int* __restrict__ bsum) {
  int g = blockIdx.y, chunk = blockIdx.x, t = threadIdx.x;
  int i = chunk * 256 + t;
  int v = (i < NN) ? ((counts[g * NN + i] + 7) & ~7) : 0;  // padded
  __shared__ int sh[256];
  sh[t] = v;
  __syncthreads();
  for (int off = 128; off > 0; off >>= 1) {
    if (t < off) sh[t] += sh[t + off];
    __syncthreads();
  }
  if (t == 0) bsum[g * NCH + chunk] = sh[0];
}

__global__ __launch_bounds__(256) void scanB_kernel(int* __restrict__ bsum,
                                                    int* __restrict__ rowptr) {
  int g = blockIdx.x, t = threadIdx.x;
  int v = (t < NCH) ? bsum[g * NCH + t] : 0;
  __shared__ int sh[256];
  sh[t] = v;
  __syncthreads();
  for (int off = 1; off < 256; off <<= 1) {
    int x = (t >= off) ? sh[t - off] : 0;
    __syncthreads();
    if (t >= off) sh[t] += x;
    __syncthreads();
  }
  if (t < NCH) bsum[g * NCH + t] = sh[t] - v;  // exclusive base
  if (t == 255) rowptr[g * (NN + 1) + NN] = sh[255];
}

__global__ __launch_bounds__(256) void scanC_kernel(const int* __restrict__ counts,
                                                    const int* __restrict__ bsum,
                                                    int* __restrict__ rowptr,
                                                    int* __restrict__ cursor,
                                                    float* __restrict__ dinv) {
  int g = blockIdx.y, chunk = blockIdx.x, t = threadIdx.x;
  int i = chunk * 256 + t;
  int c = (i < NN) ? counts[g * NN + i] : 0;
  int v = (c + 7) & ~7;  // padded
  __shared__ int sh[256];
  sh[t] = v;
  __syncthreads();
  for (int off = 1; off < 256; off <<= 1) {
    int x = (t >= off) ? sh[t - off] : 0;
    __syncthreads();
    if (t >= off) sh[t] += x;
    __syncthreads();
  }
  if (i < NN) {
    int run = bsum[g * NCH + chunk] + sh[t] - v;
    rowptr[g * (NN + 1) + i] = run;
    cursor[g * NN + i] = run;
    dinv[g * NN + i] = rsqrtf((float)(c + 1));  // true degree +1 self-loop
  }
}

__global__ void scatter_kernel(const int* __restrict__ e0, const int* __restrict__ e1,
                               int* __restrict__ cursor, unsigned short* __restrict__ col) {
  int g = blockIdx.y;
  const int* e = g ? e1 : e0;
  int* cur = cursor + g * NN;
  unsigned short* cl = col + (size_t)g * NEP;
  int i = blockIdx.x * blockDim.x + threadIdx.x;
  if (i < NE) {
    int s = e[i], d = e[NE + i];
    int slot = atomicAdd(&cur[d], 1);
    cl[slot] = (unsigned short)s;
  }
}

// ---------------- Pack W into B-fragment order ----------------
// Wpack flat index: ((kb*NT + nt)*64 + lane)*8 + j  holds W[kb*32 + (lane>>4)*8 + j][nt*16 + (lane&15)]

__global__ void pack_kernel(const float* __restrict__ W1, const float* __restrict__ W2,
                            unsigned short* __restrict__ P1, unsigned short* __restrict__ P2) {
  int i = blockIdx.x * blockDim.x + threadIdx.x;
  constexpr int N1 = 8 * 16 * 64 * 8;  // 65536 (K=256, N=256)
  constexpr int N2 = 8 * 8 * 64 * 8;   // 32768 (K=256, N=128)
  if (i < N1) {
    int j = i & 7, lane = (i >> 3) & 63, grp = i >> 9;
    int nt = grp & 15, kb = grp >> 4;
    int k = kb * 32 + (lane >> 4) * 8 + j;
    int n = nt * 16 + (lane & 15);
    P1[i] = f2bf(W1[k * DHID + n]);
  } else if (i < N1 + N2) {
    int ii = i - N1;
    int j = ii & 7, lane = (ii >> 3) & 63, grp = ii >> 9;
    int nt = grp & 7, kb = grp >> 3;
    int k = kb * 32 + (lane >> 4) * 8 + j;
    int n = nt * 16 + (lane & 15);
    P2[ii] = f2bf(W2[k * DOUT + n]);
  }
}

// ---------------- mm1: m1c = (x @ W1) * dinv[row], CHUNK-MAJOR bf16 ----------------
// m1c layout: [g][chunk 0..7][node (NNP rows)][32 cols]; chunk = col>>5.

__global__ __launch_bounds__(256) void mm1_kernel(
    const float* __restrict__ A0, const float* __restrict__ A1,
    const unsigned short* __restrict__ Wp, unsigned short* __restrict__ m1c,
    const float* __restrict__ dinv) {
  constexpr int N = DHID, NT = N / 16, K = 256;
  int g = blockIdx.y;
  const float* A = g ? A1 : A0;
  unsigned short* C = m1c + (size_t)g * 8 * NNP * 32;
  const float* dv = dinv + g * NN;
  int wave = threadIdx.x >> 6, lane = threadIdx.x & 63;
  int q = lane >> 4, lm = lane & 15;
  int m0 = blockIdx.x * 64 + wave * 16;
  int rowc = min(m0 + lm, NN - 1);
  f32x4 acc[NT];
#pragma unroll
  for (int nt = 0; nt < NT; nt++) acc[nt] = (f32x4){0.f, 0.f, 0.f, 0.f};
#pragma unroll
  for (int kb = 0; kb < K / 32; kb++) {
    int kc = kb * 32 + q * 8;
    const float* Af = A + (size_t)rowc * K + kc;
    const float4 v0 = *(const float4*)Af;
    const float4 v1 = *(const float4*)(Af + 4);
    bf16x8 a;
    a[0] = (__bf16)v0.x; a[1] = (__bf16)v0.y; a[2] = (__bf16)v0.z; a[3] = (__bf16)v0.w;
    a[4] = (__bf16)v1.x; a[5] = (__bf16)v1.y; a[6] = (__bf16)v1.z; a[7] = (__bf16)v1.w;
#pragma unroll
    for (int nt = 0; nt < NT; nt++) {
      bf16x8 b = *(const bf16x8*)(Wp + (((size_t)kb * NT + nt) * 64 + lane) * 8);
      acc[nt] = __builtin_amdgcn_mfma_f32_16x16x32_bf16(a, b, acc[nt], 0, 0, 0);
    }
  }
  float dvr[4];
#pragma unroll
  for (int r = 0; r < 4; r++) dvr[r] = dv[min(m0 + q * 4 + r, NN - 1)];
#pragma unroll
  for (int nt = 0; nt < NT; nt++) {
#pragma unroll
    for (int r = 0; r < 4; r++) {
      int grow = m0 + q * 4 + r;
      if (grow < NN)
        C[((size_t)(nt >> 1) * NNP + grow) * 32 + (nt & 1) * 16 + lm] =
            f2bf(acc[nt][r] * dvr[r]);
    }
  }
}

// ---------------- agg1c: XCD-sharded group-per-node gather (32-col chunk) --------
// chunk = blockIdx.x & 7 -> fixed XCD; slice (3.2 MB) is L2-resident.
// 4-lane group owns one node: sub=lane&3 covers cols sub*8..+7 (16 B).
// Padded CSR: segments 8-aligned, pad slots -> zero row NN. Inner loop is a
// mask-free 8-edge batch: one aligned uint4 index load + 8 uint4 row loads.
// No cross-lane reduction; direct write per group.

__global__ __launch_bounds__(256) void agg1c_kernel(
    const unsigned short* __restrict__ m1c, unsigned short* __restrict__ a1c,
    const int* __restrict__ rowptr, const unsigned short* __restrict__ col,
    const float* __restrict__ dinv, const float* __restrict__ b1) {
  int chunk = blockIdx.x & 7, nb = blockIdx.x >> 3, g = blockIdx.y;
  const unsigned short* Hc = m1c + ((size_t)g * 8 + chunk) * ((size_t)NNP * 32);
  unsigned short* Ac = a1c + ((size_t)g * 8 + chunk) * ((size_t)NNP * 32);
  const int* rp = rowptr + g * (NN + 1);
  const unsigned short* cl = col + (size_t)g * NEP;
  const float* dv = dinv + g * NN;
  int lane = threadIdx.x & 63, wave = threadIdx.x >> 6;
  int sub = lane & 3;
  int node = nb * 64 + wave * 16 + (lane >> 2);
  int nodec = min(node, NN - 1);
  float4 bb0 = *(const float4*)(b1 + chunk * 32 + sub * 8);
  float4 bb1 = *(const float4*)(b1 + chunk * 32 + sub * 8 + 4);
  int jb = rp[nodec], je = rp[nodec + 1];
  float a[8] = {0.f, 0.f, 0.f, 0.f, 0.f, 0.f, 0.f, 0.f};
  // self row
  uint4 sv = *(const uint4*)(Hc + (size_t)nodec * 32 + sub * 8);
  acc8(a, sv);
  for (int j = jb; j < je; j += 8) {
    uint4 w = *(const uint4*)(cl + j);  // 8 indices, 16B aligned (jb,j mult of 8)
    int s0 = w.x & 0xffff, s1 = w.x >> 16;
    int s2 = w.y & 0xffff, s3 = w.y >> 16;
    int s4 = w.z & 0xffff, s5 = w.z >> 16;
    int s6 = w.w & 0xffff, s7 = w.w >> 16;
    uint4 v0 = *(const uint4*)(Hc + s0 * 32 + sub * 8);
    uint4 v1 = *(const uint4*)(Hc + s1 * 32 + sub * 8);
    uint4 v2 = *(const uint4*)(Hc + s2 * 32 + sub * 8);
    uint4 v3 = *(const uint4*)(Hc + s3 * 32 + sub * 8);
    uint4 v4 = *(const uint4*)(Hc + s4 * 32 + sub * 8);
    uint4 v5 = *(const uint4*)(Hc + s5 * 32 + sub * 8);
    uint4 v6 = *(const uint4*)(Hc + s6 * 32 + sub * 8);
    uint4 v7 = *(const uint4*)(Hc + s7 * 32 + sub * 8);
    acc8(a, v0); acc8(a, v1); acc8(a, v2); acc8(a, v3);
    acc8(a, v4); acc8(a, v5); acc8(a, v6); acc8(a, v7);
  }
  float di = dv[nodec];
  us8 o;
  o[0] = f2bf(fmaxf(fmaf(a[0], di, bb0.x), 0.f));
  o[1] = f2bf(fmaxf(fmaf(a[1], di, bb0.y), 0.f));
  o[2] = f2bf(fmaxf(fmaf(a[2], di, bb0.z), 0.f));
  o[3] = f2bf(fmaxf(fmaf(a[3], di, bb0.w), 0.f));
  o[4] = f2bf(fmaxf(fmaf(a[4], di, bb1.x), 0.f));
  o[5] = f2bf(fmaxf(fmaf(a[5], di, bb1.y), 0.f));
  o[6] = f2bf(fmaxf(fmaf(a[6], di, bb1.z), 0.f));
  o[7] = f2bf(fmaxf(fmaf(a[7], di, bb1.w), 0.f));
  if (node < NN) *(us8*)(Ac + (size_t)node * 32 + sub * 8) = o;
}

// ---------------- mm2: m2c = (a1 @ W2) * dinv, dense GEMM ----------------
// a1c chunk-major IS the A-frag layout (k-chunk kb == col-chunk kb).
// m2c written chunk-major: [g][chunk 0..3][node (NNP)][32].

__global__ __launch_bounds__(256) void mm2_kernel(
    const unsigned short* __restrict__ a1c, const unsigned short* __restrict__ P2,
    unsigned short* __restrict__ m2c, const float* __restrict__ dinv) {
  constexpr int NT2 = DOUT / 16;  // 8
  int g = blockIdx.y;
  const unsigned short* A = a1c + (size_t)g * 8 * NNP * 32;
  unsigned short* C = m2c + (size_t)g * 4 * NNP * 32;
  const float* dv = dinv + g * NN;
  int wave = threadIdx.x >> 6, lane = threadIdx.x & 63;
  int q = lane >> 4, lm = lane & 15;
  int m0 = blockIdx.x * 64 + wave * 16;
  int rowc = min(m0 + lm, NN - 1);
  f32x4 acc[NT2];
#pragma unroll
  for (int nt = 0; nt < NT2; nt++) acc[nt] = (f32x4){0.f, 0.f, 0.f, 0.f};
#pragma unroll
  for (int kb = 0; kb < 8; kb++) {
    bf16x8 a = *(const bf16x8*)(A + ((size_t)kb * NNP + rowc) * 32 + q * 8);
#pragma unroll
    for (int nt = 0; nt < NT2; nt++) {
      bf16x8 b = *(const bf16x8*)(P2 + (((size_t)kb * NT2 + nt) * 64 + lane) * 8);
      acc[nt] = __builtin_amdgcn_mfma_f32_16x16x32_bf16(a, b, acc[nt], 0, 0, 0);
    }
  }
  float dvr[4];
#pragma unroll
  for (int r = 0; r < 4; r++) dvr[r] = dv[min(m0 + q * 4 + r, NN - 1)];
#pragma unroll
  for (int nt = 0; nt < NT2; nt++) {
#pragma unroll
    for (int r = 0; r < 4; r++) {
      int grow = m0 + q * 4 + r;
      if (grow < NN)
        C[((size_t)(nt >> 1) * NNP + grow) * 32 + (nt & 1) * 16 + lm] =
            f2bf(acc[nt][r] * dvr[r]);
    }
  }
}

// ---------------- agg2c: XCD-sharded group-per-node final aggregate -> out ------
// chunk = blockIdx.x & 3 (each chunk served by XCDs c and c+4); slice 3.2 MB.

__global__ __launch_bounds__(256) void agg2c_kernel(
    const unsigned short* __restrict__ m2c, float* __restrict__ out,
    const int* __restrict__ rowptr, const unsigned short* __restrict__ col,
    const float* __restrict__ dinv, const float* __restrict__ b2) {
  int chunk = blockIdx.x & 3, nb = blockIdx.x >> 2, g = blockIdx.y;
  const unsigned short* Hc = m2c + ((size_t)g * 4 + chunk) * ((size_t)NNP * 32);
  float* O = out + (size_t)g * NN * DOUT;
  const int* rp = rowptr + g * (NN + 1);
  const unsigned short* cl = col + (size_t)g * NEP;
  const float* dv = dinv + g * NN;
  int lane = threadIdx.x & 63, wave = threadIdx.x >> 6;
  int sub = lane & 3;
  int node = nb * 64 + wave * 16 + (lane >> 2);
  int nodec = min(node, NN - 1);
  float4 c0 = *(const float4*)(b2 + chunk * 32 + sub * 8);
  float4 c1 = *(const float4*)(b2 + chunk * 32 + sub * 8 + 4);
  int jb = rp[nodec], je = rp[nodec + 1];
  float a[8] = {0.f, 0.f, 0.f, 0.f, 0.f, 0.f, 0.f, 0.f};
  uint4 sv = *(const uint4*)(Hc + (size_t)nodec * 32 + sub * 8);
  acc8(a, sv);
  for (int j = jb; j < je; j += 8) {
    uint4 w = *(const uint4*)(cl + j);
    int s0 = w.x & 0xffff, s1 = w.x >> 16;
    int s2 = w.y & 0xffff, s3 = w.y >> 16;
    int s4 = w.z & 0xffff, s5 = w.z >> 16;
    int s6 = w.w & 0xffff, s7 = w.w >> 16;
    uint4 v0 = *(const uint4*)(Hc + s0 * 32 + sub * 8);
    uint4 v1 = *(const uint4*)(Hc + s1 * 32 + sub * 8);
    uint4 v2 = *(const uint4*)(Hc + s2 * 32 + sub * 8);
    uint4 v3 = *(const uint4*)(Hc + s3 * 32 + sub * 8);
    uint4 v4 = *(const uint4*)(Hc + s4 * 32 + sub * 8);
    uint4 v5 = *(const uint4*)(Hc + s5 * 32 + sub * 8);
    uint4 v6 = *(const uint4*)(Hc + s6 * 32 + sub * 8);
    uint4 v7 = *(const uint4*)(Hc + s7 * 32 + sub * 8);
    acc8(a, v0); acc8(a, v1); acc8(a, v2); acc8(a, v3);
    acc8(a, v4); acc8(a, v5); acc8(a, v6); acc8(a, v7);
  }
  if (node < NN) {
    float di = dv[node];
    float4 o0, o1;
    o0.x = fmaf(a[0], di, c0.x); o0.y = fmaf(a[1], di, c0.y);
    o0.z = fmaf(a[2], di, c0.z); o0.w = fmaf(a[3], di, c0.w);
    o1.x = fmaf(a[4], di, c1.x); o1.y = fmaf(a[5], di, c1.y);
    o1.z = fmaf(a[6], di, c1.z); o1.w = fmaf(a[7], di, c1.w);
    *(float4*)(O + (size_t)node * DOUT + chunk * 32 + sub * 8) = o0;
    *(float4*)(O + (size_t)node * DOUT + chunk * 32 + sub * 8 + 4) = o1;
  }
}

// ---------------- launch ----------------

extern "C" void kernel_launch(void* const* d_in, const int* in_sizes, int n_in,
                              void* d_out, int out_size, void* d_ws, size_t ws_size,
                              hipStream_t stream) {
  const float* x1 = (const float*)d_in[0];
  const int* e1 = (const int*)d_in[1];
  const float* x2 = (const float*)d_in[2];
  const int* e2 = (const int*)d_in[3];
  const float* W1 = (const float*)d_in[4];
  const float* b1 = (const float*)d_in[5];
  const float* W2 = (const float*)d_in[6];
  const float* b2 = (const float*)d_in[7];
  float* out = (float*)d_out;

  char* base = (char*)d_ws;
  size_t off = 0;
  auto alloc = [&](size_t bytes) -> void* {
    void* p = base + off;
    off = (off + bytes + 511) & ~(size_t)511;
    return p;
  };
  int* counts = (int*)alloc((size_t)2 * NN * 4);
  int* rowptr = (int*)alloc((size_t)2 * (NN + 1) * 4);
  int* cursor = (int*)alloc((size_t)2 * NN * 4);
  float* dinv = (float*)alloc((size_t)2 * NN * 4);
  int* bsum = (int*)alloc((size_t)2 * NCH * 4);
  unsigned short* col = (unsigned short*)alloc((size_t)2 * NEP * 2);
  unsigned short* m1c = (unsigned short*)alloc((size_t)2 * 8 * NNP * 32 * 2);
  unsigned short* a1c = (unsigned short*)alloc((size_t)2 * 8 * NNP * 32 * 2);
  unsigned short* m2c = m1c;  // reuse: m1c dead after agg1c; zero rows preserved
  unsigned short* P1 = (unsigned short*)alloc((size_t)8 * 16 * 64 * 8 * 2);
  unsigned short* P2 = (unsigned short*)alloc((size_t)8 * 8 * 64 * 8 * 2);

  fillcol_kernel<<<(2 * NEP / 8 + 255) / 256, 256, 0, stream>>>(col);
  hipMemsetAsync(counts, 0, (size_t)2 * NN * 4, stream);
  hist_kernel<<<dim3((NE + 255) / 256, 2), 256, 0, stream>>>(e1, e2, counts);
  scanA_kernel<<<dim3(NCH, 2), 256, 0, stream>>>(counts, bsum);
  scanB_kernel<<<2, 256, 0, stream>>>(bsum, rowptr);
  scanC_kernel<<<dim3(NCH, 2), 256, 0, stream>>>(counts, bsum, rowptr, cursor, dinv);
  scatter_kernel<<<dim3((NE + 255) / 256, 2), 256, 0, stream>>>(e1, e2, cursor, col);
  pack_kernel<<<(98304 + 255) / 256, 256, 0, stream>>>(W1, W2, P1, P2);
  zrow_kernel<<<1, 512, 0, stream>>>(m1c);
  // layer 1 mm: m1c = (x @ W1) * dinv (bf16, chunk-major)
  mm1_kernel<<<dim3(NGRP, 2), 256, 0, stream>>>(x1, x2, P1, m1c, dinv);
  // sharded agg1: a1c = relu(agg(m1c)*dinv + b1) per 32-col chunk (XCD-local)
  agg1c_kernel<<<dim3(8 * NGRP, 2), 256, 0, stream>>>(m1c, a1c, rowptr, col, dinv, b1);
  // layer 2 mm: m2c = (a1 @ W2) * dinv (bf16, chunk-major)
  mm2_kernel<<<dim3(NGRP, 2), 256, 0, stream>>>(a1c, P2, m2c, dinv);
  // sharded agg2: out = agg(m2c)*dinv + b2 (f32)
  agg2c_kernel<<<dim3(4 * NGRP, 2), 256, 0, stream>>>(m2c, out, rowptr, col, dinv, b2);
}

// Round 6
// 500.172 us; speedup vs baseline: 1.4672x; 1.0672x over previous
//
#include <hip/hip_runtime.h>

typedef __bf16 bf16x8 __attribute__((ext_vector_type(8)));
typedef float f32x4 __attribute__((ext_vector_type(4)));
typedef unsigned short us8 __attribute__((ext_vector_type(8)));

constexpr int NN = 50000;   // nodes
constexpr int NE = 800000;  // edges
constexpr int NNP = NN + 8;           // slice row stride (row NN = zero row)
constexpr int NEP = NE + 8 * NN;      // padded CSR capacity (1.2M slots)
constexpr int DIN = 256, DHID = 256, DOUT = 128;
constexpr int NCH = (NN + 255) / 256;  // 196 chunks of 256
constexpr int NGRP = (NN + 63) / 64;   // 782 groups of 64 nodes
constexpr int RNG = 6250;              // nodes per XCD dst-range (50000/8)

__device__ __forceinline__ unsigned short f2bf(float f) {
  unsigned u = __float_as_uint(f);
  u += 0x7fffu + ((u >> 16) & 1u);  // RNE
  return (unsigned short)(u >> 16);
}

// accumulate 8 bf16 (packed in uint4) into a[8]
__device__ __forceinline__ void acc8(float a[8], uint4 v) {
  a[0] += __uint_as_float(v.x << 16);
  a[1] += __uint_as_float(v.x & 0xffff0000u);
  a[2] += __uint_as_float(v.y << 16);
  a[3] += __uint_as_float(v.y & 0xffff0000u);
  a[4] += __uint_as_float(v.z << 16);
  a[5] += __uint_as_float(v.z & 0xffff0000u);
  a[6] += __uint_as_float(v.w << 16);
  a[7] += __uint_as_float(v.w & 0xffff0000u);
}

// ---------------- pad helpers ----------------

__global__ void fillcol_kernel(unsigned short* __restrict__ col) {
  constexpr int TOT = 2 * NEP / 8;  // uint4 count
  int i = blockIdx.x * blockDim.x + threadIdx.x;
  unsigned v = (unsigned)NN | ((unsigned)NN << 16);
  if (i < TOT) ((uint4*)col)[i] = (uint4){v, v, v, v};
}

// zero row NN of each of the 16 chunk slices (serves m1c and m2c phases)
__global__ void zrow_kernel(unsigned short* __restrict__ m1c) {
  int t = threadIdx.x;  // 512 threads = 16 slices x 32 cols
  int s = t >> 5, c = t & 31;
  m1c[(size_t)s * NNP * 32 + (size_t)NN * 32 + c] = 0;
}

// ---------------- CSR build (XCD-partitioned by dst-range) ----------------
// blockIdx.x & 7 = dst-range r (nodes [r*RNG,(r+1)*RNG)) -> fixed XCD.
// Each range-group scans ALL edges (coalesced, L3-resident) and handles only
// its own dsts: counts/cursor lines and the cl slot region for a range are
// then touched by exactly ONE XCD -> lines accumulate in that L2, writeback
// once (kills the 20x write amplification seen in the naive scatter).

__global__ void hist_kernel(const int* __restrict__ e0, const int* __restrict__ e1,
                            int* __restrict__ counts) {
  int g = blockIdx.y;
  const int* dst = (g ? e1 : e0) + NE;  // edge_index row 1
  int* c = counts + g * NN;
  int r = blockIdx.x & 7;
  int t = (blockIdx.x >> 3) * blockDim.x + threadIdx.x;
  int stride = (gridDim.x >> 3) * blockDim.x;
  for (int i = t; i < NE; i += stride) {
    int d = dst[i];
    if (d / RNG == r) atomicAdd(&c[d], 1);
  }
}

__global__ void scatter_kernel(const int* __restrict__ e0, const int* __restrict__ e1,
                               int* __restrict__ cursor, unsigned short* __restrict__ col) {
  int g = blockIdx.y;
  const int* e = g ? e1 : e0;
  int* cur = cursor + g * NN;
  unsigned short* cl = col + (size_t)g * NEP;
  int r = blockIdx.x & 7;
  int t = (blockIdx.x >> 3) * blockDim.x + threadIdx.x;
  int stride = (gridDim.x >> 3) * blockDim.x;
  for (int i = t; i < NE; i += stride) {
    int d = e[NE + i];
    if (d / RNG == r) {
      int s = e[i];
      int slot = atomicAdd(&cur[d], 1);
      cl[slot] = (unsigned short)s;
    }
  }
}

__global__ __launch_bounds__(256) void scanA_kernel(const int* __restrict__ counts,
                                                    int* __restrict__ bsum) {
  int g = blockIdx.y, chunk = blockIdx.x, t = threadIdx.x;
  int i = chunk * 256 + t;
  int v = (i < NN) ? ((counts[g * NN + i] + 7) & ~7) : 0;  // padded
  __shared__ int sh[256];
  sh[t] = v;
  __syncthreads();
  for (int off = 128; off > 0; off >>= 1) {
    if (t < off) sh[t] += sh[t + off];
    __syncthreads();
  }
  if (t == 0) bsum[g * NCH + chunk] = sh[0];
}

__global__ __launch_bounds__(256) void scanB_kernel(int* __restrict__ bsum,
                                                    int* __restrict__ rowptr) {
  int g = blockIdx.x, t = threadIdx.x;
  int v = (t < NCH) ? bsum[g * NCH + t] : 0;
  __shared__ int sh[256];
  sh[t] = v;
  __syncthreads();
  for (int off = 1; off < 256; off <<= 1) {
    int x = (t >= off) ? sh[t - off] : 0;
    __syncthreads();
    if (t >= off) sh[t] += x;
    __syncthreads();
  }
  if (t < NCH) bsum[g * NCH + t] = sh[t] - v;  // exclusive base
  if (t == 255) rowptr[g * (NN + 1) + NN] = sh[255];
}

__global__ __launch_bounds__(256) void scanC_kernel(const int* __restrict__ counts,
                                                    const int* __restrict__ bsum,
                                                    int* __restrict__ rowptr,
                                                    int* __restrict__ cursor,
                                                    float* __restrict__ dinv) {
  int g = blockIdx.y, chunk = blockIdx.x, t = threadIdx.x;
  int i = chunk * 256 + t;
  int c = (i < NN) ? counts[g * NN + i] : 0;
  int v = (c + 7) & ~7;  // padded
  __shared__ int sh[256];
  sh[t] = v;
  __syncthreads();
  for (int off = 1; off < 256; off <<= 1) {
    int x = (t >= off) ? sh[t - off] : 0;
    __syncthreads();
    if (t >= off) sh[t] += x;
    __syncthreads();
  }
  if (i < NN) {
    int run = bsum[g * NCH + chunk] + sh[t] - v;
    rowptr[g * (NN + 1) + i] = run;
    cursor[g * NN + i] = run;
    dinv[g * NN + i] = rsqrtf((float)(c + 1));  // true degree +1 self-loop
  }
}

// ---------------- Pack W into B-fragment order ----------------
// Wpack flat index: ((kb*NT + nt)*64 + lane)*8 + j  holds W[kb*32 + (lane>>4)*8 + j][nt*16 + (lane&15)]

__global__ void pack_kernel(const float* __restrict__ W1, const float* __restrict__ W2,
                            unsigned short* __restrict__ P1, unsigned short* __restrict__ P2) {
  int i = blockIdx.x * blockDim.x + threadIdx.x;
  constexpr int N1 = 8 * 16 * 64 * 8;  // 65536 (K=256, N=256)
  constexpr int N2 = 8 * 8 * 64 * 8;   // 32768 (K=256, N=128)
  if (i < N1) {
    int j = i & 7, lane = (i >> 3) & 63, grp = i >> 9;
    int nt = grp & 15, kb = grp >> 4;
    int k = kb * 32 + (lane >> 4) * 8 + j;
    int n = nt * 16 + (lane & 15);
    P1[i] = f2bf(W1[k * DHID + n]);
  } else if (i < N1 + N2) {
    int ii = i - N1;
    int j = ii & 7, lane = (ii >> 3) & 63, grp = ii >> 9;
    int nt = grp & 7, kb = grp >> 3;
    int k = kb * 32 + (lane >> 4) * 8 + j;
    int n = nt * 16 + (lane & 15);
    P2[ii] = f2bf(W2[k * DOUT + n]);
  }
}

// ---------------- mm1: m1c = (x @ W1) * dinv[row], CHUNK-MAJOR bf16 ----------------
// m1c layout: [g][chunk 0..7][node (NNP rows)][32 cols]; chunk = col>>5.

__global__ __launch_bounds__(256) void mm1_kernel(
    const float* __restrict__ A0, const float* __restrict__ A1,
    const unsigned short* __restrict__ Wp, unsigned short* __restrict__ m1c,
    const float* __restrict__ dinv) {
  constexpr int N = DHID, NT = N / 16, K = 256;
  int g = blockIdx.y;
  const float* A = g ? A1 : A0;
  unsigned short* C = m1c + (size_t)g * 8 * NNP * 32;
  const float* dv = dinv + g * NN;
  int wave = threadIdx.x >> 6, lane = threadIdx.x & 63;
  int q = lane >> 4, lm = lane & 15;
  int m0 = blockIdx.x * 64 + wave * 16;
  int rowc = min(m0 + lm, NN - 1);
  f32x4 acc[NT];
#pragma unroll
  for (int nt = 0; nt < NT; nt++) acc[nt] = (f32x4){0.f, 0.f, 0.f, 0.f};
#pragma unroll
  for (int kb = 0; kb < K / 32; kb++) {
    int kc = kb * 32 + q * 8;
    const float* Af = A + (size_t)rowc * K + kc;
    const float4 v0 = *(const float4*)Af;
    const float4 v1 = *(const float4*)(Af + 4);
    bf16x8 a;
    a[0] = (__bf16)v0.x; a[1] = (__bf16)v0.y; a[2] = (__bf16)v0.z; a[3] = (__bf16)v0.w;
    a[4] = (__bf16)v1.x; a[5] = (__bf16)v1.y; a[6] = (__bf16)v1.z; a[7] = (__bf16)v1.w;
#pragma unroll
    for (int nt = 0; nt < NT; nt++) {
      bf16x8 b = *(const bf16x8*)(Wp + (((size_t)kb * NT + nt) * 64 + lane) * 8);
      acc[nt] = __builtin_amdgcn_mfma_f32_16x16x32_bf16(a, b, acc[nt], 0, 0, 0);
    }
  }
  float dvr[4];
#pragma unroll
  for (int r = 0; r < 4; r++) dvr[r] = dv[min(m0 + q * 4 + r, NN - 1)];
#pragma unroll
  for (int nt = 0; nt < NT; nt++) {
#pragma unroll
    for (int r = 0; r < 4; r++) {
      int grow = m0 + q * 4 + r;
      if (grow < NN)
        C[((size_t)(nt >> 1) * NNP + grow) * 32 + (nt & 1) * 16 + lm] =
            f2bf(acc[nt][r] * dvr[r]);
    }
  }
}

// ---------------- agg1c: XCD-sharded group-per-node gather (32-col chunk) --------
// chunk = blockIdx.x & 7 -> fixed XCD; slice (3.2 MB) is L2-resident.
// 4-lane group owns one node: sub=lane&3 covers cols sub*8..+7 (16 B).
// Padded CSR: segments 8-aligned, pad slots -> zero row NN. Inner loop is a
// mask-free 8-edge batch: one aligned uint4 index load + 8 uint4 row loads.

__global__ __launch_bounds__(256) void agg1c_kernel(
    const unsigned short* __restrict__ m1c, unsigned short* __restrict__ a1c,
    const int* __restrict__ rowptr, const unsigned short* __restrict__ col,
    const float* __restrict__ dinv, const float* __restrict__ b1) {
  int chunk = blockIdx.x & 7, nb = blockIdx.x >> 3, g = blockIdx.y;
  const unsigned short* Hc = m1c + ((size_t)g * 8 + chunk) * ((size_t)NNP * 32);
  unsigned short* Ac = a1c + ((size_t)g * 8 + chunk) * ((size_t)NNP * 32);
  const int* rp = rowptr + g * (NN + 1);
  const unsigned short* cl = col + (size_t)g * NEP;
  const float* dv = dinv + g * NN;
  int lane = threadIdx.x & 63, wave = threadIdx.x >> 6;
  int sub = lane & 3;
  int node = nb * 64 + wave * 16 + (lane >> 2);
  int nodec = min(node, NN - 1);
  float4 bb0 = *(const float4*)(b1 + chunk * 32 + sub * 8);
  float4 bb1 = *(const float4*)(b1 + chunk * 32 + sub * 8 + 4);
  int jb = rp[nodec], je = rp[nodec + 1];
  float a[8] = {0.f, 0.f, 0.f, 0.f, 0.f, 0.f, 0.f, 0.f};
  // self row
  uint4 sv = *(const uint4*)(Hc + (size_t)nodec * 32 + sub * 8);
  acc8(a, sv);
  for (int j = jb; j < je; j += 8) {
    uint4 w = *(const uint4*)(cl + j);  // 8 indices, 16B aligned (jb,j mult of 8)
    int s0 = w.x & 0xffff, s1 = w.x >> 16;
    int s2 = w.y & 0xffff, s3 = w.y >> 16;
    int s4 = w.z & 0xffff, s5 = w.z >> 16;
    int s6 = w.w & 0xffff, s7 = w.w >> 16;
    uint4 v0 = *(const uint4*)(Hc + s0 * 32 + sub * 8);
    uint4 v1 = *(const uint4*)(Hc + s1 * 32 + sub * 8);
    uint4 v2 = *(const uint4*)(Hc + s2 * 32 + sub * 8);
    uint4 v3 = *(const uint4*)(Hc + s3 * 32 + sub * 8);
    uint4 v4 = *(const uint4*)(Hc + s4 * 32 + sub * 8);
    uint4 v5 = *(const uint4*)(Hc + s5 * 32 + sub * 8);
    uint4 v6 = *(const uint4*)(Hc + s6 * 32 + sub * 8);
    uint4 v7 = *(const uint4*)(Hc + s7 * 32 + sub * 8);
    acc8(a, v0); acc8(a, v1); acc8(a, v2); acc8(a, v3);
    acc8(a, v4); acc8(a, v5); acc8(a, v6); acc8(a, v7);
  }
  float di = dv[nodec];
  us8 o;
  o[0] = f2bf(fmaxf(fmaf(a[0], di, bb0.x), 0.f));
  o[1] = f2bf(fmaxf(fmaf(a[1], di, bb0.y), 0.f));
  o[2] = f2bf(fmaxf(fmaf(a[2], di, bb0.z), 0.f));
  o[3] = f2bf(fmaxf(fmaf(a[3], di, bb0.w), 0.f));
  o[4] = f2bf(fmaxf(fmaf(a[4], di, bb1.x), 0.f));
  o[5] = f2bf(fmaxf(fmaf(a[5], di, bb1.y), 0.f));
  o[6] = f2bf(fmaxf(fmaf(a[6], di, bb1.z), 0.f));
  o[7] = f2bf(fmaxf(fmaf(a[7], di, bb1.w), 0.f));
  if (node < NN) *(us8*)(Ac + (size_t)node * 32 + sub * 8) = o;
}

// ---------------- mm2: m2c = (a1 @ W2) * dinv, dense GEMM ----------------
// a1c chunk-major IS the A-frag layout (k-chunk kb == col-chunk kb).
// m2c written chunk-major: [g][chunk 0..3][node (NNP)][32].

__global__ __launch_bounds__(256) void mm2_kernel(
    const unsigned short* __restrict__ a1c, const unsigned short* __restrict__ P2,
    unsigned short* __restrict__ m2c, const float* __restrict__ dinv) {
  constexpr int NT2 = DOUT / 16;  // 8
  int g = blockIdx.y;
  const unsigned short* A = a1c + (size_t)g * 8 * NNP * 32;
  unsigned short* C = m2c + (size_t)g * 4 * NNP * 32;
  const float* dv = dinv + g * NN;
  int wave = threadIdx.x >> 6, lane = threadIdx.x & 63;
  int q = lane >> 4, lm = lane & 15;
  int m0 = blockIdx.x * 64 + wave * 16;
  int rowc = min(m0 + lm, NN - 1);
  f32x4 acc[NT2];
#pragma unroll
  for (int nt = 0; nt < NT2; nt++) acc[nt] = (f32x4){0.f, 0.f, 0.f, 0.f};
#pragma unroll
  for (int kb = 0; kb < 8; kb++) {
    bf16x8 a = *(const bf16x8*)(A + ((size_t)kb * NNP + rowc) * 32 + q * 8);
#pragma unroll
    for (int nt = 0; nt < NT2; nt++) {
      bf16x8 b = *(const bf16x8*)(P2 + (((size_t)kb * NT2 + nt) * 64 + lane) * 8);
      acc[nt] = __builtin_amdgcn_mfma_f32_16x16x32_bf16(a, b, acc[nt], 0, 0, 0);
    }
  }
  float dvr[4];
#pragma unroll
  for (int r = 0; r < 4; r++) dvr[r] = dv[min(m0 + q * 4 + r, NN - 1)];
#pragma unroll
  for (int nt = 0; nt < NT2; nt++) {
#pragma unroll
    for (int r = 0; r < 4; r++) {
      int grow = m0 + q * 4 + r;
      if (grow < NN)
        C[((size_t)(nt >> 1) * NNP + grow) * 32 + (nt & 1) * 16 + lm] =
            f2bf(acc[nt][r] * dvr[r]);
    }
  }
}

// ---------------- agg2c: XCD-sharded group-per-node final aggregate -> out ------
// chunk = blockIdx.x & 3 (each chunk served by XCDs c and c+4); slice 3.2 MB.

__global__ __launch_bounds__(256) void agg2c_kernel(
    const unsigned short* __restrict__ m2c, float* __restrict__ out,
    const int* __restrict__ rowptr, const unsigned short* __restrict__ col,
    const float* __restrict__ dinv, const float* __restrict__ b2) {
  int chunk = blockIdx.x & 3, nb = blockIdx.x >> 2, g = blockIdx.y;
  const unsigned short* Hc = m2c + ((size_t)g * 4 + chunk) * ((size_t)NNP * 32);
  float* O = out + (size_t)g * NN * DOUT;
  const int* rp = rowptr + g * (NN + 1);
  const unsigned short* cl = col + (size_t)g * NEP;
  const float* dv = dinv + g * NN;
  int lane = threadIdx.x & 63, wave = threadIdx.x >> 6;
  int sub = lane & 3;
  int node = nb * 64 + wave * 16 + (lane >> 2);
  int nodec = min(node, NN - 1);
  float4 c0 = *(const float4*)(b2 + chunk * 32 + sub * 8);
  float4 c1 = *(const float4*)(b2 + chunk * 32 + sub * 8 + 4);
  int jb = rp[nodec], je = rp[nodec + 1];
  float a[8] = {0.f, 0.f, 0.f, 0.f, 0.f, 0.f, 0.f, 0.f};
  uint4 sv = *(const uint4*)(Hc + (size_t)nodec * 32 + sub * 8);
  acc8(a, sv);
  for (int j = jb; j < je; j += 8) {
    uint4 w = *(const uint4*)(cl + j);
    int s0 = w.x & 0xffff, s1 = w.x >> 16;
    int s2 = w.y & 0xffff, s3 = w.y >> 16;
    int s4 = w.z & 0xffff, s5 = w.z >> 16;
    int s6 = w.w & 0xffff, s7 = w.w >> 16;
    uint4 v0 = *(const uint4*)(Hc + s0 * 32 + sub * 8);
    uint4 v1 = *(const uint4*)(Hc + s1 * 32 + sub * 8);
    uint4 v2 = *(const uint4*)(Hc + s2 * 32 + sub * 8);
    uint4 v3 = *(const uint4*)(Hc + s3 * 32 + sub * 8);
    uint4 v4 = *(const uint4*)(Hc + s4 * 32 + sub * 8);
    uint4 v5 = *(const uint4*)(Hc + s5 * 32 + sub * 8);
    uint4 v6 = *(const uint4*)(Hc + s6 * 32 + sub * 8);
    uint4 v7 = *(const uint4*)(Hc + s7 * 32 + sub * 8);
    acc8(a, v0); acc8(a, v1); acc8(a, v2); acc8(a, v3);
    acc8(a, v4); acc8(a, v5); acc8(a, v6); acc8(a, v7);
  }
  if (node < NN) {
    float di = dv[node];
    float4 o0, o1;
    o0.x = fmaf(a[0], di, c0.x); o0.y = fmaf(a[1], di, c0.y);
    o0.z = fmaf(a[2], di, c0.z); o0.w = fmaf(a[3], di, c0.w);
    o1.x = fmaf(a[4], di, c1.x); o1.y = fmaf(a[5], di, c1.y);
    o1.z = fmaf(a[6], di, c1.z); o1.w = fmaf(a[7], di, c1.w);
    *(float4*)(O + (size_t)node * DOUT + chunk * 32 + sub * 8) = o0;
    *(float4*)(O + (size_t)node * DOUT + chunk * 32 + sub * 8 + 4) = o1;
  }
}

// ---------------- launch ----------------

extern "C" void kernel_launch(void* const* d_in, const int* in_sizes, int n_in,
                              void* d_out, int out_size, void* d_ws, size_t ws_size,
                              hipStream_t stream) {
  const float* x1 = (const float*)d_in[0];
  const int* e1 = (const int*)d_in[1];
  const float* x2 = (const float*)d_in[2];
  const int* e2 = (const int*)d_in[3];
  const float* W1 = (const float*)d_in[4];
  const float* b1 = (const float*)d_in[5];
  const float* W2 = (const float*)d_in[6];
  const float* b2 = (const float*)d_in[7];
  float* out = (float*)d_out;

  char* base = (char*)d_ws;
  size_t off = 0;
  auto alloc = [&](size_t bytes) -> void* {
    void* p = base + off;
    off = (off + bytes + 511) & ~(size_t)511;
    return p;
  };
  int* counts = (int*)alloc((size_t)2 * NN * 4);
  int* rowptr = (int*)alloc((size_t)2 * (NN + 1) * 4);
  int* cursor = (int*)alloc((size_t)2 * NN * 4);
  float* dinv = (float*)alloc((size_t)2 * NN * 4);
  int* bsum = (int*)alloc((size_t)2 * NCH * 4);
  unsigned short* col = (unsigned short*)alloc((size_t)2 * NEP * 2);
  unsigned short* m1c = (unsigned short*)alloc((size_t)2 * 8 * NNP * 32 * 2);
  unsigned short* a1c = (unsigned short*)alloc((size_t)2 * 8 * NNP * 32 * 2);
  unsigned short* m2c = m1c;  // reuse: m1c dead after agg1c; zero rows preserved
  unsigned short* P1 = (unsigned short*)alloc((size_t)8 * 16 * 64 * 8 * 2);
  unsigned short* P2 = (unsigned short*)alloc((size_t)8 * 8 * 64 * 8 * 2);

  fillcol_kernel<<<(2 * NEP / 8 + 255) / 256, 256, 0, stream>>>(col);
  hipMemsetAsync(counts, 0, (size_t)2 * NN * 4, stream);
  // XCD-partitioned hist: 8 ranges x 96 slices
  hist_kernel<<<dim3(8 * 96, 2), 256, 0, stream>>>(e1, e2, counts);
  scanA_kernel<<<dim3(NCH, 2), 256, 0, stream>>>(counts, bsum);
  scanB_kernel<<<2, 256, 0, stream>>>(bsum, rowptr);
  scanC_kernel<<<dim3(NCH, 2), 256, 0, stream>>>(counts, bsum, rowptr, cursor, dinv);
  // XCD-partitioned scatter: cursor + cl region per dst-range stay in one L2
  scatter_kernel<<<dim3(8 * 96, 2), 256, 0, stream>>>(e1, e2, cursor, col);
  pack_kernel<<<(98304 + 255) / 256, 256, 0, stream>>>(W1, W2, P1, P2);
  zrow_kernel<<<1, 512, 0, stream>>>(m1c);
  // layer 1 mm: m1c = (x @ W1) * dinv (bf16, chunk-major)
  mm1_kernel<<<dim3(NGRP, 2), 256, 0, stream>>>(x1, x2, P1, m1c, dinv);
  // sharded agg1: a1c = relu(agg(m1c)*dinv + b1) per 32-col chunk (XCD-local)
  agg1c_kernel<<<dim3(8 * NGRP, 2), 256, 0, stream>>>(m1c, a1c, rowptr, col, dinv, b1);
  // layer 2 mm: m2c = (a1 @ W2) * dinv (bf16, chunk-major)
  mm2_kernel<<<dim3(NGRP, 2), 256, 0, stream>>>(a1c, P2, m2c, dinv);
  // sharded agg2: out = agg(m2c)*dinv + b2 (f32)
  agg2c_kernel<<<dim3(4 * NGRP, 2), 256, 0, stream>>>(m2c, out, rowptr, col, dinv, b2);
}